// Round 3
// baseline (203.878 us; speedup 1.0000x reference)
//
#include <hip/hip_runtime.h>

#define BB 8
#define NN 512
#define PP 32
#define SLOT (BB*NN*PP)   // 131072 floats

// ---------------------------------------------------------------------------
// K1: one wave per (l, b, n). 64 lanes own 8 m-values each (2 x float4 of w,s
// in registers -> no LDS broadcast in the hot loop). t4/t3/t2 coefficients are
// wave-uniform -> scalar loads. Per-lane acc[32] (static idx, no scratch),
// then LDS transpose-reduce + shfl_xor(32), then 32x32 matvecs.
//   t31[p][n] = sum_m relu(t4[p,1]*w[n,m] + (-0.5 t4[p,2] s_n)*s_m
//                          + (t4[p,0]x_n + 0.5 t4[p,2] + t4[p,3]))
//   base_l[n][p] = t1-term + sum_q t3[p][q] t31[q][n]
//   l==0: tmp2_1[n][p] = sum_q t2[1][p][q] relu(base0[q][n])
// Block 256 = 4 waves (4 n-rows). Grid = 3*8*128 = 3072.
// ---------------------------------------------------------------------------
__global__ __launch_bounds__(256) void k_phaseA(
    const float* __restrict__ x, const float* __restrict__ wts,
    const float* __restrict__ extra, const float* __restrict__ t1,
    const float* __restrict__ t2, const float* __restrict__ t3,
    const float* __restrict__ t4, float* __restrict__ ws)
{
    const int tid  = threadIdx.x;
    const int wv   = tid >> 6;
    const int lane = tid & 63;
    const int blk  = blockIdx.x;
    const int l  = blk >> 10;         // 0..2
    const int b  = (blk >> 7) & 7;    // 0..7
    const int nt = blk & 127;         // 0..127
    const int n  = nt*4 + wv;

    __shared__ float part[4][32][68]; // row stride 68 floats = 272B (16B-aligned)
    __shared__ float cbuf[4][32];

    const float* xrow = x + b*NN;
    const float* wrow = wts + ((size_t)b*NN + n)*NN;
    const float4 wa = *(const float4*)(wrow + lane*4);
    const float4 wb = *(const float4*)(wrow + 256 + lane*4);
    const float4 xa = *(const float4*)(xrow + lane*4);
    const float4 xb = *(const float4*)(xrow + 256 + lane*4);
    const float4 sa = { 2.f*xa.x-1.f, 2.f*xa.y-1.f, 2.f*xa.z-1.f, 2.f*xa.w-1.f };
    const float4 sb = { 2.f*xb.x-1.f, 2.f*xb.y-1.f, 2.f*xb.z-1.f, 2.f*xb.w-1.f };
    const float xn = xrow[n];
    const float en = extra[b*NN + n];
    const float sn = 2.f*xn - 1.f;

    const float* t4l = t4 + l*(PP*4);
    float acc[32];
#pragma unroll
    for (int p = 0; p < 32; ++p) {
        const float c0 = t4l[p*4+0], Ay = t4l[p*4+1];
        const float Bz = t4l[p*4+2], c3 = t4l[p*4+3];
        const float Cc = fmaf(c0, xn, fmaf(0.5f, Bz, c3));
        const float Bc = -0.5f*Bz*sn;
        float a0, a1;
        a0  = fmaxf(0.f, fmaf(Ay, wa.x, fmaf(Bc, sa.x, Cc)));
        a1  = fmaxf(0.f, fmaf(Ay, wa.y, fmaf(Bc, sa.y, Cc)));
        a0 += fmaxf(0.f, fmaf(Ay, wa.z, fmaf(Bc, sa.z, Cc)));
        a1 += fmaxf(0.f, fmaf(Ay, wa.w, fmaf(Bc, sa.w, Cc)));
        a0 += fmaxf(0.f, fmaf(Ay, wb.x, fmaf(Bc, sb.x, Cc)));
        a1 += fmaxf(0.f, fmaf(Ay, wb.y, fmaf(Bc, sb.y, Cc)));
        a0 += fmaxf(0.f, fmaf(Ay, wb.z, fmaf(Bc, sb.z, Cc)));
        a1 += fmaxf(0.f, fmaf(Ay, wb.w, fmaf(Bc, sb.w, Cc)));
        acc[p] = a0 + a1;
    }

    // transpose-reduce across 64 lanes (per-wave LDS region, no __syncthreads)
#pragma unroll
    for (int p = 0; p < 32; ++p) part[wv][p][lane] = acc[p];
    const int p2 = lane & 31, h = lane >> 5;
    float r = 0.f;
#pragma unroll
    for (int k = 0; k < 8; ++k) {
        const float4 v = *(const float4*)&part[wv][p2][h*32 + k*4];
        r += (v.x + v.y) + (v.z + v.w);
    }
    r += __shfl_xor(r, 32, 64);       // full sum over all 64 lanes
    cbuf[wv][p2] = r;                 // t31[p2][n] (both halves write same value)

    const float* t3r = t3 + l*(PP*PP) + p2*32;
    float term3 = 0.f;
#pragma unroll
    for (int q = 0; q < 8; ++q) {
        const float4 tv = *(const float4*)(t3r + q*4);
        const float4 cv = *(const float4*)&cbuf[wv][q*4];
        term3 = fmaf(tv.x,cv.x, fmaf(tv.y,cv.y, fmaf(tv.z,cv.z, fmaf(tv.w,cv.w, term3))));
    }
    const float* t1r = t1 + l*(PP*3) + p2*3;
    const float term1 = fmaf(t1r[0], 1.f-xn, fmaf(t1r[2], en, t1r[1]));
    const float basev = term1 + term3;

    if (l == 0) {
        const float mu0 = fmaxf(basev, 0.f);
        cbuf[wv][p2] = mu0;           // reads above precede in program order
        const float* t2r = t2 + PP*PP + p2*32;   // layer-1 t2
        float s0 = 0.f;
#pragma unroll
        for (int q = 0; q < 8; ++q) {
            const float4 tv = *(const float4*)(t2r + q*4);
            const float4 cv = *(const float4*)&cbuf[wv][q*4];
            s0 = fmaf(tv.x,cv.x, fmaf(tv.y,cv.y, fmaf(tv.z,cv.z, fmaf(tv.w,cv.w, s0))));
        }
        if (h == 0) ws[2*SLOT + ((size_t)(b*NN + n))*PP + p2] = s0;   // tmp2_1
    } else {
        float* dst = ws + (l == 1 ? 0 : SLOT);    // base1 / base2
        if (h == 0) dst[((size_t)(b*NN + n))*PP + p2] = basev;
    }
}

// ---------------------------------------------------------------------------
// K2/K3: block = (b, 64-j tile), 1024 threads = 16 waves, n split 16 ways.
// Wave w: for its 32 n: av = adj[n][j_lane] (coalesced); tmp2 row wave-uniform
// -> SGPR operand: acc[p] = v_fmac(s_t[p], av). Partials merged via ds_add_f32
// (2-way bank aliasing = free). Fused: +base, relu, then either t2-matvec ->
// tmp2out (coalesced via LDS) or transposed store to d_out.
// Grid = 8*8 = 64 blocks.
// ---------------------------------------------------------------------------
__global__ __launch_bounds__(1024) void k_layer(
    const float* __restrict__ adj, const float* __restrict__ t2l,
    const float* __restrict__ basein, const float* __restrict__ tmp2in,
    float* __restrict__ tmp2out, float* __restrict__ dout, int final_)
{
    const int tid  = threadIdx.x;
    const int b    = blockIdx.x >> 3;
    const int jg   = blockIdx.x & 7;
    const int j0   = jg * 64;
    const int wvu  = __builtin_amdgcn_readfirstlane(tid >> 6);  // uniform wave id
    const int lane = tid & 63;

    __shared__ float accb[64][33];    // [j][p], stride 33 -> 2-way aliasing only
    __shared__ float mub[32][64];     // mu[q][j]

    for (int i = tid; i < 64*33; i += 1024) (&accb[0][0])[i] = 0.f;
    __syncthreads();

    float acc[32];
#pragma unroll
    for (int p = 0; p < 32; ++p) acc[p] = 0.f;

    const float* adjp = adj + (size_t)b*NN*NN + j0 + lane;
    const float* tb   = tmp2in + (size_t)b*NN*PP;
#pragma unroll 4
    for (int i = 0; i < 32; ++i) {
        const int nn = wvu*32 + i;                 // wave-uniform
        const float av = adjp[(size_t)nn*NN];      // coalesced 256B
        const float* tr = tb + nn*PP;              // uniform -> s_load rows
#pragma unroll
        for (int p = 0; p < 32; ++p) acc[p] = fmaf(tr[p], av, acc[p]);
    }
#pragma unroll
    for (int p = 0; p < 32; ++p) atomicAdd(&accb[lane][p], acc[p]);
    __syncthreads();

    const int ps = wvu * 2;                        // p-pair owned by this wave
    const size_t brow = ((size_t)b*NN + j0 + lane)*PP;
    float r0 = accb[lane][ps]     + basein[brow + ps];
    float r1 = accb[lane][ps + 1] + basein[brow + ps + 1];
    r0 = fmaxf(r0, 0.f); r1 = fmaxf(r1, 0.f);

    if (final_) {
        dout[((size_t)b*PP + ps)*NN     + j0 + lane] = r0;
        dout[((size_t)b*PP + ps + 1)*NN + j0 + lane] = r1;
    } else {
        mub[ps][lane]     = r0;
        mub[ps + 1][lane] = r1;
        __syncthreads();
        const float* ta  = t2l + ps*32;            // uniform -> s_load
        const float* tbr = t2l + (ps + 1)*32;
        float o0 = 0.f, o1 = 0.f;
#pragma unroll
        for (int q = 0; q < 32; ++q) {
            const float mq = mub[q][lane];         // conflict-free (lanes consec)
            o0 = fmaf(ta[q],  mq, o0);
            o1 = fmaf(tbr[q], mq, o1);
        }
        accb[lane][ps]     = o0;                   // own slot (read above), no race
        accb[lane][ps + 1] = o1;
        __syncthreads();
        // linear coalesced store of the 64x32 tile
        float* dst = tmp2out + ((size_t)b*NN + j0)*PP;
        const int e = tid*2;
        const float v0 = accb[e >> 5][e & 31];
        const float v1 = accb[e >> 5][(e & 31) + 1];
        const float2 v = { v0, v1 };
        *(float2*)(dst + e) = v;
    }
}

extern "C" void kernel_launch(void* const* d_in, const int* in_sizes, int n_in,
                              void* d_out, int out_size, void* d_ws, size_t ws_size,
                              hipStream_t stream) {
    const float* x     = (const float*)d_in[0];
    const float* adj   = (const float*)d_in[1];
    const float* wts   = (const float*)d_in[2];
    const float* extra = (const float*)d_in[3];
    const float* t1    = (const float*)d_in[4];
    const float* t2    = (const float*)d_in[5];
    const float* t3    = (const float*)d_in[6];
    const float* t4    = (const float*)d_in[7];
    float* out = (float*)d_out;
    float* ws  = (float*)d_ws;

    float* slotA = ws;            // base1, then tmp2_2 (in place, block-disjoint)
    float* slotB = ws + SLOT;     // base2
    float* slotC = ws + 2*SLOT;   // tmp2_1

    hipLaunchKernelGGL(k_phaseA, dim3(3*BB*128), dim3(256), 0, stream,
                       x, wts, extra, t1, t2, t3, t4, ws);
    // layer 1: mu1 = relu(base1 + tmp2_1 @ adj); tmp2_2 = t2[2] @ mu1 -> slotA
    hipLaunchKernelGGL(k_layer, dim3(BB*8), dim3(1024), 0, stream,
                       adj, t2 + 2*PP*PP, slotA, slotC, slotA, (float*)nullptr, 0);
    // layer 2: mu2 = relu(base2 + tmp2_2 @ adj) -> d_out ([b][p][n])
    hipLaunchKernelGGL(k_layer, dim3(BB*8), dim3(1024), 0, stream,
                       adj, t2, slotB, slotA, (float*)nullptr, out, 1);
}

// Round 4
// 146.200 us; speedup vs baseline: 1.3945x; 1.3945x over previous
//
#include <hip/hip_runtime.h>

#define BB 8
#define NN 512
#define PP 32
#define SLOT (BB*NN*PP)   // 131072 floats

// ---------------------------------------------------------------------------
// K1: one wave per (l, b, n). 64 lanes own 8 m-values each (2 x float4 of w,s
// in registers). Per-p partial is computed in SCALARS and written straight to
// the LDS transpose buffer (no acc[32] array -> no spill risk).
//   t31[p][n] = sum_m relu(t4[p,1]*w[n,m] + (-0.5 t4[p,2] s_n)*s_m
//                          + (t4[p,0]x_n + 0.5 t4[p,2] + t4[p,3]))
//   base_l[n][p] = t1-term + sum_q t3[p][q] t31[q][n]
//   l==0: tmp2_1[n][p] = sum_q t2[1][p][q] relu(base0[q][n])
// Block 256 = 4 waves (4 n-rows). Grid = 3*8*128 = 3072.
// ---------------------------------------------------------------------------
__global__ __launch_bounds__(256) void k_phaseA(
    const float* __restrict__ x, const float* __restrict__ wts,
    const float* __restrict__ extra, const float* __restrict__ t1,
    const float* __restrict__ t2, const float* __restrict__ t3,
    const float* __restrict__ t4, float* __restrict__ ws)
{
    const int tid  = threadIdx.x;
    const int wv   = tid >> 6;
    const int lane = tid & 63;
    const int blk  = blockIdx.x;
    const int l  = blk >> 10;         // 0..2
    const int b  = (blk >> 7) & 7;    // 0..7
    const int nt = blk & 127;         // 0..127
    const int n  = nt*4 + wv;

    __shared__ float part[4][32][68]; // row stride 68 floats (16B-aligned rows)
    __shared__ float cbuf[4][32];

    const float* xrow = x + b*NN;
    const float* wrow = wts + ((size_t)b*NN + n)*NN;
    const float4 wa = *(const float4*)(wrow + lane*4);
    const float4 wb = *(const float4*)(wrow + 256 + lane*4);
    const float4 xa = *(const float4*)(xrow + lane*4);
    const float4 xb = *(const float4*)(xrow + 256 + lane*4);
    const float4 sa = { 2.f*xa.x-1.f, 2.f*xa.y-1.f, 2.f*xa.z-1.f, 2.f*xa.w-1.f };
    const float4 sb = { 2.f*xb.x-1.f, 2.f*xb.y-1.f, 2.f*xb.z-1.f, 2.f*xb.w-1.f };
    const float xn = xrow[n];
    const float en = extra[b*NN + n];
    const float sn = 2.f*xn - 1.f;

    const float* t4l = t4 + l*(PP*4);
#pragma unroll
    for (int p = 0; p < 32; ++p) {
        const float c0 = t4l[p*4+0], Ay = t4l[p*4+1];
        const float Bz = t4l[p*4+2], c3 = t4l[p*4+3];
        const float Cc = fmaf(c0, xn, fmaf(0.5f, Bz, c3));
        const float Bc = -0.5f*Bz*sn;
        float a0, a1;
        a0  = fmaxf(0.f, fmaf(Ay, wa.x, fmaf(Bc, sa.x, Cc)));
        a1  = fmaxf(0.f, fmaf(Ay, wa.y, fmaf(Bc, sa.y, Cc)));
        a0 += fmaxf(0.f, fmaf(Ay, wa.z, fmaf(Bc, sa.z, Cc)));
        a1 += fmaxf(0.f, fmaf(Ay, wa.w, fmaf(Bc, sa.w, Cc)));
        a0 += fmaxf(0.f, fmaf(Ay, wb.x, fmaf(Bc, sb.x, Cc)));
        a1 += fmaxf(0.f, fmaf(Ay, wb.y, fmaf(Bc, sb.y, Cc)));
        a0 += fmaxf(0.f, fmaf(Ay, wb.z, fmaf(Bc, sb.z, Cc)));
        a1 += fmaxf(0.f, fmaf(Ay, wb.w, fmaf(Bc, sb.w, Cc)));
        part[wv][p][lane] = a0 + a1;          // straight to LDS, no acc[] array
    }

    // transpose-reduce across 64 lanes (per-wave region, in-wave ordering)
    const int p2 = lane & 31, h = lane >> 5;
    float r = 0.f;
#pragma unroll
    for (int k = 0; k < 8; ++k) {
        const float4 v = *(const float4*)&part[wv][p2][h*32 + k*4];
        r += (v.x + v.y) + (v.z + v.w);
    }
    r += __shfl_xor(r, 32, 64);       // full sum over all 64 lanes
    cbuf[wv][p2] = r;                 // t31[p2][n]

    const float* t3r = t3 + l*(PP*PP) + p2*32;
    float term3 = 0.f;
#pragma unroll
    for (int q = 0; q < 8; ++q) {
        const float4 tv = *(const float4*)(t3r + q*4);
        const float4 cv = *(const float4*)&cbuf[wv][q*4];
        term3 = fmaf(tv.x,cv.x, fmaf(tv.y,cv.y, fmaf(tv.z,cv.z, fmaf(tv.w,cv.w, term3))));
    }
    const float* t1r = t1 + l*(PP*3) + p2*3;
    const float term1 = fmaf(t1r[0], 1.f-xn, fmaf(t1r[2], en, t1r[1]));
    const float basev = term1 + term3;

    if (l == 0) {
        const float mu0 = fmaxf(basev, 0.f);
        cbuf[wv][p2] = mu0;
        const float* t2r = t2 + PP*PP + p2*32;   // layer-1 t2
        float s0 = 0.f;
#pragma unroll
        for (int q = 0; q < 8; ++q) {
            const float4 tv = *(const float4*)(t2r + q*4);
            const float4 cv = *(const float4*)&cbuf[wv][q*4];
            s0 = fmaf(tv.x,cv.x, fmaf(tv.y,cv.y, fmaf(tv.z,cv.z, fmaf(tv.w,cv.w, s0))));
        }
        if (h == 0) ws[2*SLOT + ((size_t)(b*NN + n))*PP + p2] = s0;   // tmp2_1
    } else {
        float* dst = ws + (l == 1 ? 0 : SLOT);    // base1 / base2
        if (h == 0) dst[((size_t)(b*NN + n))*PP + p2] = basev;
    }
}

// ---------------------------------------------------------------------------
// K2/K3: block = (b, 64-j tile), 512 thr = 8 waves.
// Wave w: n-half hh=w>>2, p-octet ww=w&3 (wave-uniform -> tmp2 rows on the
// SCALAR path: s_load + SGPR-operand v_fma). Lane = j -> adj reads coalesced,
// each adj element fetched exactly once chip-wide. acc[8] only (no spill).
// Partials via padded LDS; fused +base, relu, then t2-matvec or final store.
// Grid = 8*8 = 64 blocks.
// ---------------------------------------------------------------------------
__global__ __launch_bounds__(512) void k_layer(
    const float* __restrict__ adj, const float* __restrict__ t2l,
    const float* __restrict__ basein, const float* __restrict__ tmp2in,
    float* __restrict__ tmp2out, float* __restrict__ dout, int final_)
{
    const int tid  = threadIdx.x;
    const int b    = blockIdx.x >> 3;
    const int jt   = blockIdx.x & 7;
    const int j0   = jt * 64;
    const int w    = __builtin_amdgcn_readfirstlane(tid >> 6);  // wave id 0..7
    const int lane = tid & 63;
    const int hh   = w >> 2;          // n-half
    const int ww   = w & 3;           // p-octet

    __shared__ float part[2][32][66]; // [half][p][j], stride 66 -> conflict-free
    __shared__ float mub[32][66];     // mu[q][j]

    float acc[8];
#pragma unroll
    for (int i = 0; i < 8; ++i) acc[i] = 0.f;

    const float* adjp = adj + (size_t)b*NN*NN + (size_t)(hh*256)*NN + j0 + lane;
    const float* trp  = tmp2in + (size_t)b*NN*PP + (size_t)(hh*256)*PP + ww*8;

#pragma unroll 8
    for (int n = 0; n < 256; ++n) {
        const float av = adjp[(size_t)n*NN];          // coalesced 256B/wave
        const float4 ta = *(const float4*)(trp + n*PP);     // wave-uniform ->
        const float4 tb = *(const float4*)(trp + n*PP + 4); // scalar loads
        acc[0] = fmaf(ta.x, av, acc[0]);
        acc[1] = fmaf(ta.y, av, acc[1]);
        acc[2] = fmaf(ta.z, av, acc[2]);
        acc[3] = fmaf(ta.w, av, acc[3]);
        acc[4] = fmaf(tb.x, av, acc[4]);
        acc[5] = fmaf(tb.y, av, acc[5]);
        acc[6] = fmaf(tb.z, av, acc[6]);
        acc[7] = fmaf(tb.w, av, acc[7]);
    }
#pragma unroll
    for (int i = 0; i < 8; ++i) part[hh][ww*8 + i][lane] = acc[i];
    __syncthreads();

    // combine: thread t -> (j = t&63, p-quad pg = t>>6 [uniform])
    const int j  = tid & 63;
    const int pg = tid >> 6;
    const float4 bs = *(const float4*)(basein + ((size_t)b*NN + j0 + j)*PP + pg*4);
    float r0 = part[0][pg*4+0][j] + part[1][pg*4+0][j] + bs.x;
    float r1 = part[0][pg*4+1][j] + part[1][pg*4+1][j] + bs.y;
    float r2 = part[0][pg*4+2][j] + part[1][pg*4+2][j] + bs.z;
    float r3 = part[0][pg*4+3][j] + part[1][pg*4+3][j] + bs.w;
    r0 = fmaxf(r0, 0.f); r1 = fmaxf(r1, 0.f);
    r2 = fmaxf(r2, 0.f); r3 = fmaxf(r3, 0.f);

    if (final_) {
        dout[((size_t)b*PP + pg*4+0)*NN + j0 + j] = r0;
        dout[((size_t)b*PP + pg*4+1)*NN + j0 + j] = r1;
        dout[((size_t)b*PP + pg*4+2)*NN + j0 + j] = r2;
        dout[((size_t)b*PP + pg*4+3)*NN + j0 + j] = r3;
    } else {
        mub[pg*4+0][j] = r0;
        mub[pg*4+1][j] = r1;
        mub[pg*4+2][j] = r2;
        mub[pg*4+3][j] = r3;
        __syncthreads();   // also drains base loads before tmp2out overwrite

        const float* t0 = t2l + (pg*4+0)*32;   // uniform rows -> s_load
        const float* t1r = t2l + (pg*4+1)*32;
        const float* t2r = t2l + (pg*4+2)*32;
        const float* t3r = t2l + (pg*4+3)*32;
        float o0 = 0.f, o1 = 0.f, o2 = 0.f, o3 = 0.f;
#pragma unroll
        for (int qc = 0; qc < 8; ++qc) {
            const float m0 = mub[qc*4+0][j];
            const float m1 = mub[qc*4+1][j];
            const float m2 = mub[qc*4+2][j];
            const float m3 = mub[qc*4+3][j];
            const float4 a0 = *(const float4*)(t0  + qc*4);
            const float4 a1 = *(const float4*)(t1r + qc*4);
            const float4 a2 = *(const float4*)(t2r + qc*4);
            const float4 a3 = *(const float4*)(t3r + qc*4);
            o0 = fmaf(a0.x,m0, fmaf(a0.y,m1, fmaf(a0.z,m2, fmaf(a0.w,m3, o0))));
            o1 = fmaf(a1.x,m0, fmaf(a1.y,m1, fmaf(a1.z,m2, fmaf(a1.w,m3, o1))));
            o2 = fmaf(a2.x,m0, fmaf(a2.y,m1, fmaf(a2.z,m2, fmaf(a2.w,m3, o2))));
            o3 = fmaf(a3.x,m0, fmaf(a3.y,m1, fmaf(a3.z,m2, fmaf(a3.w,m3, o3))));
        }
        const float4 ov = { o0, o1, o2, o3 };
        *(float4*)(tmp2out + ((size_t)b*NN + j0 + j)*PP + pg*4) = ov;
    }
}

extern "C" void kernel_launch(void* const* d_in, const int* in_sizes, int n_in,
                              void* d_out, int out_size, void* d_ws, size_t ws_size,
                              hipStream_t stream) {
    const float* x     = (const float*)d_in[0];
    const float* adj   = (const float*)d_in[1];
    const float* wts   = (const float*)d_in[2];
    const float* extra = (const float*)d_in[3];
    const float* t1    = (const float*)d_in[4];
    const float* t2    = (const float*)d_in[5];
    const float* t3    = (const float*)d_in[6];
    const float* t4    = (const float*)d_in[7];
    float* out = (float*)d_out;
    float* ws  = (float*)d_ws;

    float* slotA = ws;            // base1, then tmp2_2 (in place, block-disjoint)
    float* slotB = ws + SLOT;     // base2
    float* slotC = ws + 2*SLOT;   // tmp2_1

    hipLaunchKernelGGL(k_phaseA, dim3(3*BB*128), dim3(256), 0, stream,
                       x, wts, extra, t1, t2, t3, t4, ws);
    // layer 1: mu1 = relu(base1 + tmp2_1 @ adj); tmp2_2 = t2[2] @ mu1 -> slotA
    hipLaunchKernelGGL(k_layer, dim3(BB*8), dim3(512), 0, stream,
                       adj, t2 + 2*PP*PP, slotA, slotC, slotA, (float*)nullptr, 0);
    // layer 2: mu2 = relu(base2 + tmp2_2 @ adj) -> d_out ([b][p][n])
    hipLaunchKernelGGL(k_layer, dim3(BB*8), dim3(512), 0, stream,
                       adj, t2, slotB, slotA, (float*)nullptr, out, 1);
}

// Round 5
// 121.635 us; speedup vs baseline: 1.6761x; 1.2020x over previous
//
#include <hip/hip_runtime.h>

#define BB 8
#define NN 512
#define PP 32

// ws layout (float offsets)
#define OFF_BASE1 0
#define OFF_BASE2 131072
#define OFF_T21   262144
#define OFF_T22   393216
#define OFF_PART  524288   // 4 copies x 131072 floats

// ---------------------------------------------------------------------------
// K1 (phaseA): grid 1024 x 256thr (4 waves); wave handles 3 units (l,b,n).
// t4 staged ONCE in LDS (broadcast ds_read per p -> no global latency chain).
//   t31[p][n] = sum_m relu(t4[p,1]*w[n,m] + (-0.5 t4[p,2] s_n)*s_m
//                          + (t4[p,0]x_n + 0.5 t4[p,2] + t4[p,3]))
//   base_l[n][p] = t1-term + sum_q t3[p][q] t31[q][n]
//   l==0: tmp2_1[n][p] = sum_q t2[1][p][q] relu(base0[q][n])
// ---------------------------------------------------------------------------
__global__ __launch_bounds__(256) void k_phaseA(
    const float* __restrict__ x, const float* __restrict__ wts,
    const float* __restrict__ extra, const float* __restrict__ t1,
    const float* __restrict__ t2, const float* __restrict__ t3,
    const float* __restrict__ t4, float* __restrict__ ws)
{
    const int tid  = threadIdx.x;
    const int wv   = tid >> 6;
    const int lane = tid & 63;

    __shared__ float4 t4lds[3][32];     // 1.5KB, [l][p] = 4 coeffs
    __shared__ float part[4][32][68];   // 34.8KB transpose buffer (per wave)
    __shared__ float cbuf[4][32];

    if (tid < 96) t4lds[0][tid] = ((const float4*)t4)[tid];
    __syncthreads();

    const int wgid = blockIdx.x * 4 + wv;
#pragma unroll 1
    for (int k = 0; k < 3; ++k) {
        const int u = wgid * 3 + k;
        const int l = u >> 12;
        const int b = (u >> 9) & 7;
        const int n = u & 511;

        const float* xrow = x + b*NN;
        const float* wrow = wts + ((size_t)b*NN + n)*NN;
        const float4 wa = *(const float4*)(wrow + lane*4);
        const float4 wb = *(const float4*)(wrow + 256 + lane*4);
        const float4 xa = *(const float4*)(xrow + lane*4);
        const float4 xb = *(const float4*)(xrow + 256 + lane*4);
        const float4 sa = { 2.f*xa.x-1.f, 2.f*xa.y-1.f, 2.f*xa.z-1.f, 2.f*xa.w-1.f };
        const float4 sb = { 2.f*xb.x-1.f, 2.f*xb.y-1.f, 2.f*xb.z-1.f, 2.f*xb.w-1.f };
        const float xn = xrow[n];
        const float en = extra[b*NN + n];
        const float sn = 2.f*xn - 1.f;

#pragma unroll
        for (int p = 0; p < 32; ++p) {
            const float4 c4 = t4lds[l][p];      // LDS broadcast
            const float Ay = c4.y;
            const float Cc = fmaf(c4.x, xn, fmaf(0.5f, c4.z, c4.w));
            const float Bc = -0.5f*c4.z*sn;
            float a0, a1;
            a0  = fmaxf(0.f, fmaf(Ay, wa.x, fmaf(Bc, sa.x, Cc)));
            a1  = fmaxf(0.f, fmaf(Ay, wa.y, fmaf(Bc, sa.y, Cc)));
            a0 += fmaxf(0.f, fmaf(Ay, wa.z, fmaf(Bc, sa.z, Cc)));
            a1 += fmaxf(0.f, fmaf(Ay, wa.w, fmaf(Bc, sa.w, Cc)));
            a0 += fmaxf(0.f, fmaf(Ay, wb.x, fmaf(Bc, sb.x, Cc)));
            a1 += fmaxf(0.f, fmaf(Ay, wb.y, fmaf(Bc, sb.y, Cc)));
            a0 += fmaxf(0.f, fmaf(Ay, wb.z, fmaf(Bc, sb.z, Cc)));
            a1 += fmaxf(0.f, fmaf(Ay, wb.w, fmaf(Bc, sb.w, Cc)));
            part[wv][p][lane] = a0 + a1;
        }

        // transpose-reduce across the wave (wave-local LDS, program-order safe)
        const int p2 = lane & 31, h = lane >> 5;
        float r = 0.f;
#pragma unroll
        for (int q = 0; q < 8; ++q) {
            const float4 v = *(const float4*)&part[wv][p2][h*32 + q*4];
            r += (v.x + v.y) + (v.z + v.w);
        }
        r += __shfl_xor(r, 32, 64);
        cbuf[wv][p2] = r;                       // t31[p2][n]

        const float* t3r = t3 + l*(PP*PP) + p2*32;
        float term3 = 0.f;
#pragma unroll
        for (int q = 0; q < 8; ++q) {
            const float4 tv = *(const float4*)(t3r + q*4);
            const float4 cv = *(const float4*)&cbuf[wv][q*4];
            term3 = fmaf(tv.x,cv.x, fmaf(tv.y,cv.y, fmaf(tv.z,cv.z, fmaf(tv.w,cv.w, term3))));
        }
        const float* t1r = t1 + l*(PP*3) + p2*3;
        const float term1 = fmaf(t1r[0], 1.f-xn, fmaf(t1r[2], en, t1r[1]));
        const float basev = term1 + term3;

        if (l == 0) {
            const float mu0 = fmaxf(basev, 0.f);
            cbuf[wv][p2] = mu0;
            const float* t2r = t2 + PP*PP + p2*32;   // layer-1 t2
            float s0 = 0.f;
#pragma unroll
            for (int q = 0; q < 8; ++q) {
                const float4 tv = *(const float4*)(t2r + q*4);
                const float4 cv = *(const float4*)&cbuf[wv][q*4];
                s0 = fmaf(tv.x,cv.x, fmaf(tv.y,cv.y, fmaf(tv.z,cv.z, fmaf(tv.w,cv.w, s0))));
            }
            if (h == 0) ws[OFF_T21 + ((size_t)(b*NN + n))*PP + p2] = s0;
        } else {
            float* dst = ws + (l == 1 ? OFF_BASE1 : OFF_BASE2);
            if (h == 0) dst[((size_t)(b*NN + n))*PP + p2] = basev;
        }
    }
}

// ---------------------------------------------------------------------------
// K2 (partial): grid 256 = (b, jt8, nq4), 512 thr = 8 waves (ww p-octet x hh
// n-half). tmp2 128-row slab staged in LDS (broadcast reads). adj coalesced,
// each element fetched once. In-block combine of 2 halves -> one partial copy.
// ---------------------------------------------------------------------------
__global__ __launch_bounds__(512) void k_partial(
    const float* __restrict__ adj, const float* __restrict__ tmp2in,
    float* __restrict__ partout, int b_, int unused)
{
    const int tid = threadIdx.x;
    const int blk = blockIdx.x;
    const int b   = blk >> 5;
    const int jt  = (blk >> 2) & 7;
    const int nq  = blk & 3;
    const int w   = tid >> 6;
    const int lane= tid & 63;
    const int ww  = w & 3;     // p-octet
    const int hh  = w >> 2;    // n-half (64 rows)

    __shared__ float tlds[128*32];      // 16KB tmp2 slab
    __shared__ float comb[2][32][66];   // 16.9KB

    const float* src = tmp2in + ((size_t)b*NN + nq*128)*PP;
#pragma unroll
    for (int t = 0; t < 2; ++t) {
        const int i4 = t*512 + tid;     // 0..1023 float4s
        ((float4*)tlds)[i4] = ((const float4*)src)[i4];
    }
    __syncthreads();

    float acc[8] = {0.f,0.f,0.f,0.f,0.f,0.f,0.f,0.f};
    const float* adjp = adj + ((size_t)b*NN + nq*128 + hh*64)*NN + jt*64 + lane;
    const float* trow = tlds + (hh*64)*32 + ww*8;
#pragma unroll 8
    for (int i = 0; i < 64; ++i) {
        const float av = adjp[(size_t)i*NN];        // coalesced 256B/wave
        const float4 ta = *(const float4*)(trow + i*32);      // broadcast
        const float4 tb = *(const float4*)(trow + i*32 + 4);  // broadcast
        acc[0] = fmaf(ta.x, av, acc[0]);
        acc[1] = fmaf(ta.y, av, acc[1]);
        acc[2] = fmaf(ta.z, av, acc[2]);
        acc[3] = fmaf(ta.w, av, acc[3]);
        acc[4] = fmaf(tb.x, av, acc[4]);
        acc[5] = fmaf(tb.y, av, acc[5]);
        acc[6] = fmaf(tb.z, av, acc[6]);
        acc[7] = fmaf(tb.w, av, acc[7]);
    }
#pragma unroll
    for (int t = 0; t < 8; ++t) comb[hh][ww*8 + t][lane] = acc[t];
    __syncthreads();

    const int j  = tid & 63;
    const int pg = tid >> 6;
    float4 o;
    o.x = comb[0][pg*4+0][j] + comb[1][pg*4+0][j];
    o.y = comb[0][pg*4+1][j] + comb[1][pg*4+1][j];
    o.z = comb[0][pg*4+2][j] + comb[1][pg*4+2][j];
    o.w = comb[0][pg*4+3][j] + comb[1][pg*4+3][j];
    float* pdst = partout + ((((size_t)nq*BB + b)*8 + jt)*64 + j)*PP + pg*4;
    *(float4*)pdst = o;
}

// ---------------------------------------------------------------------------
// K3 (reduce): grid 64 = (b, jt8), 512 thr. Sum 4 nq-partials + base, relu.
//   !final: tmp2out[j][p] = t2l-matvec over mu (muT LDS exchange)
//    final: d_out[b][p][j]
// ---------------------------------------------------------------------------
__global__ __launch_bounds__(512) void k_reduce(
    const float* __restrict__ basein, const float* __restrict__ partin,
    const float* __restrict__ t2l, float* __restrict__ tmp2out,
    float* __restrict__ dout, int final_)
{
    const int tid = threadIdx.x;
    const int b   = blockIdx.x >> 3;
    const int jt  = blockIdx.x & 7;
    const int j   = tid & 63;
    const int pg  = tid >> 6;

    __shared__ float muT[32][66];

    const size_t pbase = ((((size_t)b)*8 + jt)*64 + j)*PP + pg*4;
    const float4 s0 = *(const float4*)(partin + pbase);
    const float4 s1 = *(const float4*)(partin + 131072 + pbase);
    const float4 s2 = *(const float4*)(partin + 262144 + pbase);
    const float4 s3 = *(const float4*)(partin + 393216 + pbase);
    const float4 bs = *(const float4*)(basein + ((size_t)b*NN + jt*64 + j)*PP + pg*4);
    float r0 = fmaxf((s0.x+s1.x) + (s2.x+s3.x) + bs.x, 0.f);
    float r1 = fmaxf((s0.y+s1.y) + (s2.y+s3.y) + bs.y, 0.f);
    float r2 = fmaxf((s0.z+s1.z) + (s2.z+s3.z) + bs.z, 0.f);
    float r3 = fmaxf((s0.w+s1.w) + (s2.w+s3.w) + bs.w, 0.f);

    if (final_) {
        dout[((size_t)b*PP + pg*4+0)*NN + jt*64 + j] = r0;
        dout[((size_t)b*PP + pg*4+1)*NN + jt*64 + j] = r1;
        dout[((size_t)b*PP + pg*4+2)*NN + jt*64 + j] = r2;
        dout[((size_t)b*PP + pg*4+3)*NN + jt*64 + j] = r3;
    } else {
        muT[pg*4+0][j] = r0;
        muT[pg*4+1][j] = r1;
        muT[pg*4+2][j] = r2;
        muT[pg*4+3][j] = r3;
        __syncthreads();

        const float* ta = t2l + (pg*4+0)*32;
        const float* tb = t2l + (pg*4+1)*32;
        const float* tc = t2l + (pg*4+2)*32;
        const float* td = t2l + (pg*4+3)*32;
        float o0=0.f, o1=0.f, o2=0.f, o3=0.f;
#pragma unroll
        for (int qc = 0; qc < 8; ++qc) {
            const float m0 = muT[qc*4+0][j];
            const float m1 = muT[qc*4+1][j];
            const float m2 = muT[qc*4+2][j];
            const float m3 = muT[qc*4+3][j];
            const float4 a0 = *(const float4*)(ta + qc*4);
            const float4 a1 = *(const float4*)(tb + qc*4);
            const float4 a2 = *(const float4*)(tc + qc*4);
            const float4 a3 = *(const float4*)(td + qc*4);
            o0 = fmaf(a0.x,m0, fmaf(a0.y,m1, fmaf(a0.z,m2, fmaf(a0.w,m3, o0))));
            o1 = fmaf(a1.x,m0, fmaf(a1.y,m1, fmaf(a1.z,m2, fmaf(a1.w,m3, o1))));
            o2 = fmaf(a2.x,m0, fmaf(a2.y,m1, fmaf(a2.z,m2, fmaf(a2.w,m3, o2))));
            o3 = fmaf(a3.x,m0, fmaf(a3.y,m1, fmaf(a3.z,m2, fmaf(a3.w,m3, o3))));
        }
        const float4 ov = { o0, o1, o2, o3 };
        *(float4*)(tmp2out + ((size_t)b*NN + jt*64 + j)*PP + pg*4) = ov;
    }
}

extern "C" void kernel_launch(void* const* d_in, const int* in_sizes, int n_in,
                              void* d_out, int out_size, void* d_ws, size_t ws_size,
                              hipStream_t stream) {
    const float* x     = (const float*)d_in[0];
    const float* adj   = (const float*)d_in[1];
    const float* wts   = (const float*)d_in[2];
    const float* extra = (const float*)d_in[3];
    const float* t1    = (const float*)d_in[4];
    const float* t2    = (const float*)d_in[5];
    const float* t3    = (const float*)d_in[6];
    const float* t4    = (const float*)d_in[7];
    float* out = (float*)d_out;
    float* ws  = (float*)d_ws;

    float* base1 = ws + OFF_BASE1;
    float* base2 = ws + OFF_BASE2;
    float* t21   = ws + OFF_T21;
    float* t22   = ws + OFF_T22;
    float* part  = ws + OFF_PART;

    hipLaunchKernelGGL(k_phaseA, dim3(1024), dim3(256), 0, stream,
                       x, wts, extra, t1, t2, t3, t4, ws);
    // layer 1
    hipLaunchKernelGGL(k_partial, dim3(256), dim3(512), 0, stream,
                       adj, t21, part, 0, 0);
    hipLaunchKernelGGL(k_reduce, dim3(64), dim3(512), 0, stream,
                       base1, part, t2 + 2*PP*PP, t22, (float*)nullptr, 0);
    // layer 2
    hipLaunchKernelGGL(k_partial, dim3(256), dim3(512), 0, stream,
                       adj, t22, part, 0, 0);
    hipLaunchKernelGGL(k_reduce, dim3(64), dim3(512), 0, stream,
                       base2, part, (const float*)t2, (float*)nullptr, out, 1);
}